// Round 7
// baseline (323.621 us; speedup 1.0000x reference)
//
#include <hip/hip_runtime.h>

#define B_ 256
#define T_ 1024
#define V_ 5000
#define D_ 100
#define H_ 64
#define C_ 2

typedef float f32x4 __attribute__((ext_vector_type(4)));

#define SCALE_ 2.885390081777927f   // 2*log2(e): exp2(SCALE*x) == e^{2x}

// ---------------------------------------------------------------------------
// Kernel 1: EW[v][h] = 2*log2e*(sum_d E[v][d]*W[d][h] + b[h])   (unchanged)
// ---------------------------------------------------------------------------
__global__ __launch_bounds__(256) void ew_kernel(const float* __restrict__ E,
                                                 const float* __restrict__ W,
                                                 const float* __restrict__ bias,
                                                 float* __restrict__ EW) {
    int idx = blockIdx.x * 256 + threadIdx.x;   // 0 .. V_*H_
    if (idx >= V_ * H_) return;
    int h = idx & (H_ - 1);
    int v = idx >> 6;
    float acc = bias[h];
    const float* Erow = E + v * D_;
    #pragma unroll 4
    for (int d = 0; d < D_; ++d) {
        acc = fmaf(Erow[d], W[d * H_ + h], acc);
    }
    EW[idx] = SCALE_ * acc;
}

// ---------------------------------------------------------------------------
// Kernel 2: RNN, one wave per batch element, 256 blocks (= CU count).
// R11 theory: the per-iteration xw register-rotation copies (xw0=xw2 etc.)
// are USES of the freshly issued EW loads -- if the compiler schedules them
// (and their vmcnt wait) before/between the steps, every 2-step iteration
// exposes ~200 cyc of L2 latency. That matches the ~580-660 cyc/step
// invariant across ALL broadcast variants (R4/R7/R9/R10): ~440 issue +
// ~150 unexplained stall.
// Fix: unroll x8 with TWO alternating xw packs, zero rotation copies:
//   compute A(t..t+3) -> reload A(t+8..t+11) -> compute B(t+4..t+7)
//   -> reload B(t+12..t+15)
// First use of any load is a full body (~3000 cyc) later; first-use vmcnt
// is trivially satisfied. sh_tok pad grows to 8 (tail reloads hit EW[0]).
// DOT_GROUP kept VERBATIM from R10 (isolated change); uq pin now 1x/8steps.
// ---------------------------------------------------------------------------
__device__ __forceinline__ float readlane_f(float v, int lane) {
    return __uint_as_float(__builtin_amdgcn_readlane(__float_as_uint(v), lane));
}

__global__ __launch_bounds__(64, 1) void rnn_kernel(const int* __restrict__ tokens,
                                                    const float* __restrict__ EW,
                                                    const float* __restrict__ U,
                                                    const float* __restrict__ Wd,
                                                    const float* __restrict__ bd,
                                                    float* __restrict__ out) {
    const int b = blockIdx.x;     // batch element
    const int j = threadIdx.x;    // 0..63 : hidden unit

    __shared__ alignas(16) int sh_tok[T_ + 8];   // pad 8: kills all tail guards

    // --- (2*log2e)*U column j -> 16 float4 (64 VGPRs). Coalesced. ---
    f32x4 uq[16];
    #pragma unroll
    for (int c = 0; c < 16; ++c) {
        uq[c][0] = SCALE_ * U[(4 * c + 0) * H_ + j];
        uq[c][1] = SCALE_ * U[(4 * c + 1) * H_ + j];
        uq[c][2] = SCALE_ * U[(4 * c + 2) * H_ + j];
        uq[c][3] = SCALE_ * U[(4 * c + 3) * H_ + j];
    }
    // SINGLE pin: all 64 values live in VGPRs at once (R7/R9/R10-verified).
    asm volatile("" : "+v"(uq[0]), "+v"(uq[1]), "+v"(uq[2]), "+v"(uq[3]),
                      "+v"(uq[4]), "+v"(uq[5]), "+v"(uq[6]), "+v"(uq[7]),
                      "+v"(uq[8]), "+v"(uq[9]), "+v"(uq[10]), "+v"(uq[11]),
                      "+v"(uq[12]), "+v"(uq[13]), "+v"(uq[14]), "+v"(uq[15]));

    const int* tok = tokens + b * T_;
    #pragma unroll
    for (int k = 0; k < T_ / H_; ++k) {
        sh_tok[k * H_ + j] = tok[k * H_ + j];    // coalesced
    }
    if (j < 8) sh_tok[T_ + j] = 0;               // pad
    __syncthreads();

    float h = 0.f;
    float pooled = 0.f;

    // ---- 8-step pipeline: packs A (t..t+3) and B (t+4..t+7) ----
    int4  tkA = *(const int4*)&sh_tok[0];
    int4  tkB = *(const int4*)&sh_tok[4];
    float xwA0 = EW[tkA.x * H_ + j], xwA1 = EW[tkA.y * H_ + j];
    float xwA2 = EW[tkA.z * H_ + j], xwA3 = EW[tkA.w * H_ + j];
    float xwB0 = EW[tkB.x * H_ + j], xwB1 = EW[tkB.y * H_ + j];
    float xwB2 = EW[tkB.z * H_ + j], xwB3 = EW[tkB.w * H_ + j];

    // one group: 8 hazard-free readlanes (distinct SGPRs) then 8 FMAs
    #define DOT_GROUP(g)                                                 \
    {                                                                    \
        float s0 = readlane_f(h, 8 * (g) + 0);                           \
        float s1 = readlane_f(h, 8 * (g) + 1);                           \
        float s2 = readlane_f(h, 8 * (g) + 2);                           \
        float s3 = readlane_f(h, 8 * (g) + 3);                           \
        float s4 = readlane_f(h, 8 * (g) + 4);                           \
        float s5 = readlane_f(h, 8 * (g) + 5);                           \
        float s6 = readlane_f(h, 8 * (g) + 6);                           \
        float s7 = readlane_f(h, 8 * (g) + 7);                           \
        asm volatile("" : "+s"(s0), "+s"(s1), "+s"(s2), "+s"(s3),        \
                          "+s"(s4), "+s"(s5), "+s"(s6), "+s"(s7));       \
        a0 = fmaf(s0, uq[2 * (g) + 0][0], a0);                           \
        a1 = fmaf(s1, uq[2 * (g) + 0][1], a1);                           \
        a2 = fmaf(s2, uq[2 * (g) + 0][2], a2);                           \
        a3 = fmaf(s3, uq[2 * (g) + 0][3], a3);                           \
        a0 = fmaf(s4, uq[2 * (g) + 1][0], a0);                           \
        a1 = fmaf(s5, uq[2 * (g) + 1][1], a1);                           \
        a2 = fmaf(s6, uq[2 * (g) + 1][2], a2);                           \
        a3 = fmaf(s7, uq[2 * (g) + 1][3], a3);                           \
    }

    // one recurrence step: grouped hazard-free broadcast + pinned-reg U
    #define RNN_STEP(tokv, xwv)                                          \
    {                                                                    \
        float a0 = (xwv), a1 = 0.f, a2 = 0.f, a3 = 0.f;                  \
        DOT_GROUP(0) DOT_GROUP(1) DOT_GROUP(2) DOT_GROUP(3)              \
        DOT_GROUP(4) DOT_GROUP(5) DOT_GROUP(6) DOT_GROUP(7)              \
        float x2 = (a0 + a1) + (a2 + a3);                                \
        float ef = __builtin_amdgcn_exp2f(x2);                           \
        float r = __builtin_amdgcn_rcpf(ef + 1.f);                       \
        float hn = fmaf(-2.f, r, 1.f);                                   \
        h = ((tokv) != 0) ? hn : h;                                      \
        pooled += h;                                                     \
    }

    for (int t = 0; t < T_; t += 8) {
        // in-loop pin (1x per 8 steps): spilling uq would force reloads here.
        asm volatile("" :: "v"(uq[0]), "v"(uq[1]), "v"(uq[2]), "v"(uq[3]),
                           "v"(uq[4]), "v"(uq[5]), "v"(uq[6]), "v"(uq[7]),
                           "v"(uq[8]), "v"(uq[9]), "v"(uq[10]), "v"(uq[11]),
                           "v"(uq[12]), "v"(uq[13]), "v"(uq[14]), "v"(uq[15]));

        // compute steps t..t+3 from pack A
        RNN_STEP(tkA.x, xwA0);
        RNN_STEP(tkA.y, xwA1);
        RNN_STEP(tkA.z, xwA2);
        RNN_STEP(tkA.w, xwA3);

        // reload pack A with steps t+8..t+11 (pad -> EW[0], unused)
        tkA = *(const int4*)&sh_tok[t + 8];
        xwA0 = EW[tkA.x * H_ + j];
        xwA1 = EW[tkA.y * H_ + j];
        xwA2 = EW[tkA.z * H_ + j];
        xwA3 = EW[tkA.w * H_ + j];

        // compute steps t+4..t+7 from pack B
        RNN_STEP(tkB.x, xwB0);
        RNN_STEP(tkB.y, xwB1);
        RNN_STEP(tkB.z, xwB2);
        RNN_STEP(tkB.w, xwB3);

        // reload pack B with steps t+12..t+15 (pad -> EW[0], unused)
        tkB = *(const int4*)&sh_tok[t + 12];
        xwB0 = EW[tkB.x * H_ + j];
        xwB1 = EW[tkB.y * H_ + j];
        xwB2 = EW[tkB.z * H_ + j];
        xwB3 = EW[tkB.w * H_ + j];
    }
    #undef RNN_STEP
    #undef DOT_GROUP

    // ---- epilogue: pooled mean -> dense(2) -> sigmoid ----
    float p = pooled * (1.0f / (float)T_);
    float v0 = p * Wd[j * C_ + 0];
    float v1 = p * Wd[j * C_ + 1];
    #pragma unroll
    for (int off = 32; off >= 1; off >>= 1) {
        v0 += __shfl_down(v0, off, 64);
        v1 += __shfl_down(v1, off, 64);
    }
    if (j == 0) {
        float l0 = v0 + bd[0];
        float l1 = v1 + bd[1];
        out[b * C_ + 0] = 1.f / (1.f + __expf(-l0));
        out[b * C_ + 1] = 1.f / (1.f + __expf(-l1));
    }
}

// ---------------------------------------------------------------------------
extern "C" void kernel_launch(void* const* d_in, const int* in_sizes, int n_in,
                              void* d_out, int out_size, void* d_ws, size_t ws_size,
                              hipStream_t stream) {
    const int*   tokens = (const int*)  d_in[0];  // [B,T] int32
    const float* E      = (const float*)d_in[1];  // [V,D]
    const float* W      = (const float*)d_in[2];  // [D,H]
    const float* U      = (const float*)d_in[3];  // [H,H]
    const float* bias   = (const float*)d_in[4];  // [H]
    const float* Wd     = (const float*)d_in[5];  // [H,C]
    const float* bd     = (const float*)d_in[6];  // [C]
    float* out = (float*)d_out;                   // [B,C]
    float* EW  = (float*)d_ws;                    // [V,H] scratch: 1.28 MB

    ew_kernel<<<(V_ * H_ + 255) / 256, 256, 0, stream>>>(E, W, bias, EW);
    rnn_kernel<<<B_, H_, 0, stream>>>(tokens, EW, U, Wd, bd, out);
}